// Round 12
// baseline (451.508 us; speedup 1.0000x reference)
//
#include <hip/hip_runtime.h>

typedef _Float16 f16;
typedef _Float16 f16x8 __attribute__((ext_vector_type(8)));
typedef float    f32x4 __attribute__((ext_vector_type(4)));

// ws layout (bytes)
#define OFF_WHP   0u          // f16 [5][16nt][8kk][64lane][8e]   = 655360 B
#define OFF_WLP   655360u     // f16 [8kk][64lane][8e]            = 8192 B
#define OFF_W0P   663552u     // f32 [8kk][64lane][8e][4i]        = 65536 B
#define OFF_B0P   729088u     // f32 [8kk][64lane][8e]            = 16384 B
#define OFF_GP    745472u     // f32 [3j][8kk][64lane][8e]        = 49152 B
#define OFF_BHP   794624u     // f32 [5l][16nt][64lane][4r]       = 81920 B

// k-slot map: slot (kk, lane-group g, elem e) -> k = (2kk+(e>>2))*16+4g+(e&3).
// Same map on A (prepacked weights) and B (activations): MFMA D-output
// (n = nt*16+4g+r) lands exactly in B-slot (kk'=nt>>1, e'=(nt&1)*4+r).
__device__ __forceinline__ int phi(int kk, int g, int e){
  return (kk*2 + (e>>2))*16 + g*4 + (e&3);
}

__device__ __forceinline__ float tanh_fast(float z){
  float e = __builtin_amdgcn_exp2f(z * 2.885390081777927f);
  return 1.f - 2.f*__builtin_amdgcn_rcpf(e + 1.f);
}

__global__ void prepack(const float* __restrict__ W0, const float* __restrict__ b0,
                        const float* __restrict__ Wh, const float* __restrict__ bh,
                        const float* __restrict__ Wl, unsigned char* __restrict__ ws){
  int tid = blockIdx.x*256 + threadIdx.x;
  f16*   whp = (f16*)(ws + OFF_WHP);
  f16*   wlp = (f16*)(ws + OFF_WLP);
  float* w0p = (float*)(ws + OFF_W0P);
  float* b0p = (float*)(ws + OFF_B0P);
  float* gp  = (float*)(ws + OFF_GP);
  float* bhp = (float*)(ws + OFF_BHP);
  if (tid < 327680){                      // Wh fragments, f16
    int e=tid&7, lane=(tid>>3)&63, kk=(tid>>9)&7, nt=(tid>>12)&15, l=tid>>16;
    int k = phi(kk, lane>>4, e);
    int n = nt*16 + (lane&15);
    whp[tid] = (f16)Wh[(l*256 + k)*256 + n];
  } else if (tid < 331776){               // Wl fragments (N padded 3->16), f16
    int t = tid - 327680;
    int e=t&7, lane=(t>>3)&63, kk=t>>9;
    int k = phi(kk, lane>>4, e);
    int n = lane&15;
    wlp[t] = (n<3) ? (f16)Wl[k*3+n] : (f16)0.f;
  } else if (tid < 335872){               // W0 columns + b0 in slot order, f32
    int t = tid - 331776;
    int e=t&7, lane=(t>>3)&63, kk=t>>9;
    int k = phi(kk, lane>>4, e);
    #pragma unroll
    for(int i=0;i<4;i++) w0p[t*4+i] = W0[i*256+k];
    b0p[t] = b0[k];
  } else if (tid < 348160){               // g_j = W0[j,:] @ Wh[0], slot order, f32
    int t = tid - 335872;
    int e=t&7, lane=(t>>3)&63, kk=(t>>9)&7, j=t>>12;
    int k = phi(kk, lane>>4, e);
    float acc = 0.f;
    for(int k0=0;k0<256;k0++) acc = fmaf(W0[j*256+k0], Wh[k0*256+k], acc);
    gp[t] = acc;
  } else if (tid < 368640){               // bh in D-layout order, f32
    int t = tid - 348160;
    int r=t&3, lane=(t>>2)&63, nt=(t>>8)&15, l=t>>12;
    bhp[t] = bh[l*256 + nt*16 + (lane>>4)*4 + r];
  }
}

// Lane-local chunk layout (writer lane == reader lane), XOR bank swizzle.
__device__ __forceinline__ int moff(int lane, int kk){
  return lane*128 + ((kk ^ (lane & 7)) << 4);
}

// R12: n-split occupancy fix. R9/R10/R11 (traffic/2, reg-prefetch, LDS-staged
// weights) all ~0% -> weight path exonerated. Invariant: 2 waves/SIMD, both
// pipes ~19%, ~2.4k cyc/nt vs ~150 cyc MFMA = latency-bound at min occupancy.
// Per-wave unified reg demand (~190) is the occupancy wall (R5/R6 cliffs).
// Split hidden dim: 8 waves (comp c x half h), wave computes nt in [8h,8h+8).
// Persistent state halves (st only, 32 VGPR; D-outs go straight to LDS xbuf
// exchange) -> fits 128-reg cap -> 4 waves/SIMD. Layer = {A: st=mask*xbuf;
// bar; B: MFMA sweep -> xbuf/mbuf; bar}.
__global__ __launch_bounds__(512, 4) void velcurl(
    const float* __restrict__ x, const unsigned char* __restrict__ ws,
    float* __restrict__ out){
  __shared__ __align__(16) char xbuf[4][8192];   // [c][lane][chunk] activations
  __shared__ __align__(16) char mbuf[2][8192];   // [parity][lane][chunk] masks
  __shared__ float outt[3][3][16];               // [j][n][s] Jacobian rows

  const int lane  = threadIdx.x & 63;
  const int W     = threadIdx.x >> 6;   // 8 waves
  const int c     = W & 3;              // 0 = primal, 1..3 = tangent j=c-1
  const int h     = W >> 2;             // n-half: nt in [8h, 8h+8)
  const int s     = lane & 15;
  const int sbase = blockIdx.x << 4;    // 16 samples per block

  const f16x8* __restrict__ whp = (const f16x8*)(ws + OFF_WHP);
  const f16x8* __restrict__ wlp = (const f16x8*)(ws + OFF_WLP);
  const f32x4* __restrict__ w0p = (const f32x4*)(ws + OFF_W0P);
  const float* __restrict__ b0p = (const float*)(ws + OFF_B0P);
  const float* __restrict__ gp  = (const float*)(ws + OFF_GP);
  const f32x4* __restrict__ bhp = (const f32x4*)(ws + OFF_BHP);

  f16x8 st[8];   // full-K operand frags (only persistent state)

  // ---- p0: primal waves build layer-0 st, MFMA own half, publish ----
  if (c==0){
    const f32x4 xv = ((const f32x4*)x)[sbase + s];
    #pragma unroll
    for(int kk=0;kk<8;kk++){
      f16x8 v;
      #pragma unroll
      for(int e=0;e<8;e++){
        f32x4 wv = w0p[(kk*64+lane)*8+e];
        float b  = b0p[(kk*64+lane)*8+e];
        v[e] = (f16)fmaf(xv[3],wv[3], fmaf(xv[2],wv[2], fmaf(xv[1],wv[1], fmaf(xv[0],wv[0], b))));
      }
      st[kk] = v;
    }
    const f32x4* bp = bhp;
    #pragma unroll
    for(int q=0;q<4;q++){
      const int nt0 = 8*h + 2*q;
      f32x4 a0 = {0.f,0.f,0.f,0.f}, a1 = {0.f,0.f,0.f,0.f};
      #pragma unroll
      for(int kk=0;kk<8;kk++){
        f16x8 f0 = whp[((nt0  )*8+kk)*64+lane];
        f16x8 f1 = whp[((nt0+1)*8+kk)*64+lane];
        a0 = __builtin_amdgcn_mfma_f32_16x16x32_f16(f0, st[kk], a0, 0,0,0);
        a1 = __builtin_amdgcn_mfma_f32_16x16x32_f16(f1, st[kk], a1, 0,0,0);
      }
      f32x4 b0v = bp[nt0*64+lane], b1v = bp[(nt0+1)*64+lane];
      f16x8 hv, mv;
      #pragma unroll
      for(int r=0;r<4;r++){
        float h0 = tanh_fast(a0[r]+b0v[r]);
        float h1 = tanh_fast(a1[r]+b1v[r]);
        hv[r] = (f16)h0;  hv[4+r] = (f16)h1;
        mv[r] = (f16)(1.f-h0*h0);  mv[4+r] = (f16)(1.f-h1*h1);
      }
      *(f16x8*)(&xbuf[0][0] + moff(lane, 4*h+q)) = hv;
      *(f16x8*)(&mbuf[0][0] + moff(lane, 4*h+q)) = mv;
    }
  }
  __syncthreads();

  // ---- p1..p4: A(build st) | barrier | B(MFMA+publish) | barrier ----
  #pragma unroll 1
  for(int p=1;p<5;p++){
    const f16x8* wl = whp + p*8192;
    // phase A
    if (c==0){
      #pragma unroll
      for(int kk=0;kk<8;kk++)
        st[kk] = *(const f16x8*)(&xbuf[0][0] + moff(lane, kk));
    } else if (p==1){
      const int j = c-1;
      const f32x4* gpv = (const f32x4*)gp;
      #pragma unroll
      for(int kk=0;kk<8;kk++){
        f16x8 m8 = *(const f16x8*)(&mbuf[0][0] + moff(lane, kk));
        f32x4 g0 = gpv[((j*8+kk)*64+lane)*2+0];
        f32x4 g1 = gpv[((j*8+kk)*64+lane)*2+1];
        f16x8 v;
        #pragma unroll
        for(int e=0;e<8;e++){
          float gv = (e<4) ? g0[e&3] : g1[e&3];
          v[e] = (f16)((float)m8[e] * gv);
        }
        st[kk] = v;
      }
    } else {
      #pragma unroll
      for(int kk=0;kk<8;kk++){
        f16x8 m8 = *(const f16x8*)(&mbuf[(p-1)&1][0] + moff(lane, kk));
        f16x8 x8 = *(const f16x8*)(&xbuf[c][0] + moff(lane, kk));
        st[kk] = m8 * x8;
      }
    }
    __syncthreads();   // A-reads complete before B overwrites

    // phase B
    if (c==0){
      const f32x4* bp = bhp + p*1024;
      #pragma unroll
      for(int q=0;q<4;q++){
        const int nt0 = 8*h + 2*q;
        f32x4 a0 = {0.f,0.f,0.f,0.f}, a1 = {0.f,0.f,0.f,0.f};
        #pragma unroll
        for(int kk=0;kk<8;kk++){
          f16x8 f0 = wl[((nt0  )*8+kk)*64+lane];
          f16x8 f1 = wl[((nt0+1)*8+kk)*64+lane];
          a0 = __builtin_amdgcn_mfma_f32_16x16x32_f16(f0, st[kk], a0, 0,0,0);
          a1 = __builtin_amdgcn_mfma_f32_16x16x32_f16(f1, st[kk], a1, 0,0,0);
        }
        f32x4 b0v = bp[nt0*64+lane], b1v = bp[(nt0+1)*64+lane];
        f16x8 hv, mv;
        #pragma unroll
        for(int r=0;r<4;r++){
          float h0 = tanh_fast(a0[r]+b0v[r]);
          float h1 = tanh_fast(a1[r]+b1v[r]);
          hv[r] = (f16)h0;  hv[4+r] = (f16)h1;
          mv[r] = (f16)(1.f-h0*h0);  mv[4+r] = (f16)(1.f-h1*h1);
        }
        *(f16x8*)(&xbuf[0][0] + moff(lane, 4*h+q)) = hv;
        *(f16x8*)(&mbuf[p&1][0] + moff(lane, 4*h+q)) = mv;
      }
    } else {
      #pragma unroll
      for(int q=0;q<4;q++){
        const int nt0 = 8*h + 2*q;
        f32x4 a0 = {0.f,0.f,0.f,0.f}, a1 = {0.f,0.f,0.f,0.f};
        #pragma unroll
        for(int kk=0;kk<8;kk++){
          f16x8 f0 = wl[((nt0  )*8+kk)*64+lane];
          f16x8 f1 = wl[((nt0+1)*8+kk)*64+lane];
          a0 = __builtin_amdgcn_mfma_f32_16x16x32_f16(f0, st[kk], a0, 0,0,0);
          a1 = __builtin_amdgcn_mfma_f32_16x16x32_f16(f1, st[kk], a1, 0,0,0);
        }
        f16x8 v;
        #pragma unroll
        for(int r=0;r<4;r++){ v[r] = (f16)a0[r]; v[4+r] = (f16)a1[r]; }
        *(f16x8*)(&xbuf[c][0] + moff(lane, 4*h+q)) = v;
      }
    }
    __syncthreads();   // B-writes visible
  }

  // ---- p5: tangent final (mask4 in mbuf[0]) -> Wl; h==0 waves only ----
  if (c>0 && h==0){
    f32x4 acc = {0.f,0.f,0.f,0.f};
    #pragma unroll
    for(int kk=0;kk<8;kk++){
      f16x8 m8 = *(const f16x8*)(&mbuf[0][0] + moff(lane, kk));
      f16x8 x8 = *(const f16x8*)(&xbuf[c][0] + moff(lane, kk));
      acc = __builtin_amdgcn_mfma_f32_16x16x32_f16(wlp[kk*64+lane], m8*x8, acc, 0,0,0);
    }
    // D: col=lane&15=s, row=(lane>>4)*4+reg -> lanes 0..15 hold rows 0..3
    if (lane<16){
      outt[c-1][0][lane] = acc[0];
      outt[c-1][1][lane] = acc[1];
      outt[c-1][2][lane] = acc[2];
    }
  }
  __syncthreads();

  if (W==0 && lane<16){
    const int so = (sbase + lane)*3;
    out[so+0] = outt[1][2][lane] - outt[2][1][lane];  // da2/dx1 - da1/dx2
    out[so+1] = outt[2][0][lane] - outt[0][2][lane];  // da0/dx2 - da2/dx0
    out[so+2] = outt[0][1][lane] - outt[1][0][lane];  // da1/dx0 - da0/dx1
  }
}

extern "C" void kernel_launch(void* const* d_in, const int* in_sizes, int n_in,
                              void* d_out, int out_size, void* d_ws, size_t ws_size,
                              hipStream_t stream){
  const float* x  = (const float*)d_in[0];
  const float* W0 = (const float*)d_in[1];
  const float* b0 = (const float*)d_in[2];
  const float* Wh = (const float*)d_in[3];
  const float* bh = (const float*)d_in[4];
  const float* Wl = (const float*)d_in[5];
  // d_in[6] = bl: constant offset of a, curl kills it.
  prepack<<<1440, 256, 0, stream>>>(W0, b0, Wh, bh, Wl, (unsigned char*)d_ws);
  velcurl<<<4096, 512, 0, stream>>>(x, (const unsigned char*)d_ws, (float*)d_out);
}